// Round 1
// baseline (420.203 us; speedup 1.0000x reference)
//
#include <hip/hip_runtime.h>
#include <stdint.h>

#define NN 262144            // 512*512
#define EPSV 1e-5f

typedef float f32x4 __attribute__((ext_vector_type(4)));
typedef short bf16x8 __attribute__((ext_vector_type(8)));
typedef unsigned short u16t;
typedef unsigned int u32t;

__device__ __forceinline__ u16t f2bf(float f) {
  u32t u = __builtin_bit_cast(u32t, f);
  u += 0x7fff + ((u >> 16) & 1);           // RNE
  return (u16t)(u >> 16);
}
__device__ __forceinline__ float bf2f(u16t h) {
  u32t u = ((u32t)h) << 16;
  return __builtin_bit_cast(float, u);
}
__device__ __forceinline__ float sigm(float x) { return 1.0f / (1.0f + __expf(-x)); }

// ---------------- K0: weight prep ----------------
// w5: [5][128][128] bf16 = {g1,l1,g2,l2,gate}; w3: W'[o][c]=out_w*ln_out_w bf16
// S1[o] = sum_c W'[o][c]; S2[o] = sum_c ln_out_b[c]*out_w[o][c] + out_b[o]
__global__ void k0_prep(const float* __restrict__ g1w, const float* __restrict__ l1w,
                        const float* __restrict__ g2w, const float* __restrict__ l2w,
                        const float* __restrict__ gatew,
                        const float* __restrict__ outw, const float* __restrict__ outb,
                        const float* __restrict__ lnow, const float* __restrict__ lnob,
                        u16t* __restrict__ w5, u16t* __restrict__ w3,
                        float* __restrict__ S1, float* __restrict__ S2) {
  const int o = blockIdx.x;
  const int t = threadIdx.x;     // 64 threads
  float s1 = 0.f, s2 = 0.f;
  #pragma unroll
  for (int h = 0; h < 2; ++h) {
    const int c = t + 64*h;
    const int idx = o*128 + c;
    w5[0*16384 + idx] = f2bf(g1w[idx]);
    w5[1*16384 + idx] = f2bf(l1w[idx]);
    w5[2*16384 + idx] = f2bf(g2w[idx]);
    w5[3*16384 + idx] = f2bf(l2w[idx]);
    w5[4*16384 + idx] = f2bf(gatew[idx]);
    const float ow = outw[idx];
    const float wp = ow * lnow[c];
    w3[idx] = f2bf(wp);
    s1 += wp;
    s2 += lnob[c] * ow;
  }
  #pragma unroll
  for (int m = 1; m < 64; m <<= 1) { s1 += __shfl_xor(s1, m); s2 += __shfl_xor(s2, m); }
  if (t == 0) { S1[o] = s1; S2[o] = s2 + outb[o]; }
}

// stage a [128][128] bf16 matrix into padded LDS [128][136]
__device__ __forceinline__ void stage_w(u16t* dst_lds, const u16t* __restrict__ src, int t) {
  #pragma unroll
  for (int it = 0; it < 8; ++it) {
    const int ci = (it << 8) + t;
    const int row = ci >> 4, ch = ci & 15;
    *(bf16x8*)(dst_lds + row*136 + (ch << 3)) = *(const bf16x8*)(src + (row << 7) + (ch << 3));
  }
}

// C[128 rows][128 cols] = z @ W^T over K=128 (both LDS [128][136], row-major, read as row l&15 + 8 contig k)
__device__ __forceinline__ void gemm128(const u16t* zl, const u16t* wl,
                                        int rowbase, int l15, int l4, f32x4 acc[2][8]) {
  const f32x4 Z4 = {0.f, 0.f, 0.f, 0.f};
  #pragma unroll
  for (int rf = 0; rf < 2; ++rf)
    #pragma unroll
    for (int cf = 0; cf < 8; ++cf) acc[rf][cf] = Z4;
  #pragma unroll
  for (int ks = 0; ks < 4; ++ks) {
    const int ko = (ks << 5) + (l4 << 3);
    bf16x8 a0 = *(const bf16x8*)(zl + (rowbase + l15)*136 + ko);
    bf16x8 a1 = *(const bf16x8*)(zl + (rowbase + 16 + l15)*136 + ko);
    #pragma unroll
    for (int cf = 0; cf < 8; ++cf) {
      bf16x8 b = *(const bf16x8*)(wl + ((cf << 4) + l15)*136 + ko);
      acc[0][cf] = __builtin_amdgcn_mfma_f32_16x16x32_bf16(a0, b, acc[0][cf], 0, 0, 0);
      acc[1][cf] = __builtin_amdgcn_mfma_f32_16x16x32_bf16(a1, b, acc[1][cf], 0, 0, 0);
    }
  }
}

// ---------------- K1: LN + 5 linears ----------------
// block = 128 rows of (i,k)-space. Outputs: At/Bt [c][i][k] bf16, G [i][j][c] bf16
__global__ __launch_bounds__(256)
void k1_fused(const float* __restrict__ pair, const float* __restrict__ msk,
              const float* __restrict__ lnpw, const float* __restrict__ lnpb,
              const u16t* __restrict__ w5,
              const float* __restrict__ g1b, const float* __restrict__ l1b,
              const float* __restrict__ g2b, const float* __restrict__ l2b,
              const float* __restrict__ gateb,
              u16t* __restrict__ At, u16t* __restrict__ Bt, u16t* __restrict__ Gm) {
  __shared__ u16t z_lds[128*136];
  __shared__ u16t w_lds[128*136];   // weight tile; reused as transpose-staging
  const int t = threadIdx.x;
  const int blk = blockIdx.x;
  const int r0 = blk << 7;          // global row base (i*512+k space)
  const int x  = blk >> 2;          // i
  const int y0 = (blk & 3) << 7;    // k base

  // Phase A: layernorm -> z_lds bf16
  {
    const int c = (t & 31) << 2;
    const f32x4 lw = *(const f32x4*)(lnpw + c);
    const f32x4 lb = *(const f32x4*)(lnpb + c);
    #pragma unroll
    for (int v = 0; v < 16; ++v) {
      const int row = (v << 3) + (t >> 5);
      f32x4 xv = *(const f32x4*)(pair + (size_t)(r0 + row)*128 + c);
      float s = xv[0] + xv[1] + xv[2] + xv[3];
      float q = xv[0]*xv[0] + xv[1]*xv[1] + xv[2]*xv[2] + xv[3]*xv[3];
      #pragma unroll
      for (int m = 1; m <= 16; m <<= 1) { s += __shfl_xor(s, m); q += __shfl_xor(q, m); }
      const float mu = s * 0.0078125f;
      const float var = q * 0.0078125f - mu*mu;
      const float rs = rsqrtf(var + EPSV);
      const u32t lo = (u32t)f2bf((xv[0]-mu)*rs*lw[0]+lb[0]) | ((u32t)f2bf((xv[1]-mu)*rs*lw[1]+lb[1]) << 16);
      const u32t hi = (u32t)f2bf((xv[2]-mu)*rs*lw[2]+lb[2]) | ((u32t)f2bf((xv[3]-mu)*rs*lw[3]+lb[3]) << 16);
      *(uint2*)(&z_lds[row*136 + c]) = make_uint2(lo, hi);
    }
  }
  __syncthreads();

  const int wv = t >> 6, l = t & 63;
  const int l15 = l & 15, l4 = l >> 4;
  const int rowbase = wv << 5;
  f32x4 accg[2][8], accl[2][8];

  // two (gate,linear) pairs -> A then B
  #pragma unroll 1
  for (int p = 0; p < 2; ++p) {
    const float* gbp = p ? g2b : g1b;
    const float* lbp = p ? l2b : l1b;
    u16t* dst = p ? Bt : At;
    stage_w(w_lds, w5 + (size_t)(2*p)*16384, t); __syncthreads();
    gemm128(z_lds, w_lds, rowbase, l15, l4, accg);
    __syncthreads();
    stage_w(w_lds, w5 + (size_t)(2*p+1)*16384, t); __syncthreads();
    gemm128(z_lds, w_lds, rowbase, l15, l4, accl);
    __syncthreads();   // all waves done reading w_lds; reuse as transpose staging [c][r]
    #pragma unroll
    for (int rf = 0; rf < 2; ++rf) {
      const int rb = rowbase + (rf << 4) + (l4 << 2);
      const f32x4 m4 = *(const f32x4*)(msk + r0 + rb);
      #pragma unroll
      for (int cf = 0; cf < 8; ++cf) {
        const int c = (cf << 4) + l15;
        const float bg = gbp[c], bl = lbp[c];
        const float v0 = sigm(accg[rf][cf][0] + bg) * (accl[rf][cf][0] + bl) * m4[0];
        const float v1 = sigm(accg[rf][cf][1] + bg) * (accl[rf][cf][1] + bl) * m4[1];
        const float v2 = sigm(accg[rf][cf][2] + bg) * (accl[rf][cf][2] + bl) * m4[2];
        const float v3 = sigm(accg[rf][cf][3] + bg) * (accl[rf][cf][3] + bl) * m4[3];
        const u32t lo = (u32t)f2bf(v0) | ((u32t)f2bf(v1) << 16);
        const u32t hi = (u32t)f2bf(v2) | ((u32t)f2bf(v3) << 16);
        *(uint2*)(&w_lds[c*136 + rb]) = make_uint2(lo, hi);
      }
    }
    __syncthreads();
    // coalesced channel-major write: [c][x*512 + y0 + r]
    #pragma unroll
    for (int qq = 0; qq < 32; ++qq) {
      const int c = (wv << 5) + qq;
      const u32t d = *(const u32t*)(&w_lds[c*136 + (l << 1)]);
      *(u32t*)(dst + (size_t)c*NN + (size_t)x*512 + y0 + (l << 1)) = d;
    }
    __syncthreads();
  }

  // gate: G = sigmoid(z@gate^T + b), layout [row][c]
  stage_w(w_lds, w5 + (size_t)4*16384, t); __syncthreads();
  gemm128(z_lds, w_lds, rowbase, l15, l4, accg);
  #pragma unroll
  for (int rf = 0; rf < 2; ++rf) {
    #pragma unroll
    for (int cf = 0; cf < 8; ++cf) {
      const int c = (cf << 4) + l15;
      const float bg = gateb[c];
      #pragma unroll
      for (int r = 0; r < 4; ++r) {
        const int row = rowbase + (rf << 4) + (l4 << 2) + r;
        Gm[(size_t)(r0 + row)*128 + c] = f2bf(sigm(accg[rf][cf][r] + bg));
      }
    }
  }
}

// ---------------- K2: per-channel triangle GEMM ----------------
// vals[c][i][j] = sum_k A[c][i][k] * B[c][j][k]; 128x128 tile, K=512
__global__ __launch_bounds__(256)
void k2_tri(const u16t* __restrict__ At, const u16t* __restrict__ Bt, u16t* __restrict__ Vt) {
  __shared__ u16t a_lds[128*72];
  __shared__ u16t b_lds[128*72];
  const int t = threadIdx.x;
  const int blk = blockIdx.x;
  const int c  = blk >> 4;
  const int it = (blk >> 2) & 3;
  const int jt = blk & 3;
  const u16t* Ab = At + (size_t)c*NN + (size_t)(it << 7)*512;
  const u16t* Bb = Bt + (size_t)c*NN + (size_t)(jt << 7)*512;
  const int wv = t >> 6, l = t & 63;
  const int l15 = l & 15, l4 = l >> 4;
  const int wi = wv >> 1, wj = wv & 1;
  const int srow = t >> 3, sch = t & 7;

  const f32x4 Z4 = {0.f, 0.f, 0.f, 0.f};
  f32x4 acc[4][4];
  #pragma unroll
  for (int i = 0; i < 4; ++i)
    #pragma unroll
    for (int j = 0; j < 4; ++j) acc[i][j] = Z4;

  for (int kt = 0; kt < 8; ++kt) {
    const int kb = kt << 6;
    bf16x8 ra[4], rb[4];
    #pragma unroll
    for (int is = 0; is < 4; ++is) {
      const int row = (is << 5) + srow;
      ra[is] = *(const bf16x8*)(Ab + (size_t)row*512 + kb + (sch << 3));
      rb[is] = *(const bf16x8*)(Bb + (size_t)row*512 + kb + (sch << 3));
    }
    __syncthreads();                // previous iter's LDS reads done
    #pragma unroll
    for (int is = 0; is < 4; ++is) {
      const int row = (is << 5) + srow;
      *(bf16x8*)(&a_lds[row*72 + (sch << 3)]) = ra[is];
      *(bf16x8*)(&b_lds[row*72 + (sch << 3)]) = rb[is];
    }
    __syncthreads();
    #pragma unroll
    for (int ks = 0; ks < 2; ++ks) {
      const int ko = (ks << 5) + (l4 << 3);
      bf16x8 af[4], bfr[4];
      #pragma unroll
      for (int f = 0; f < 4; ++f) {
        af[f]  = *(const bf16x8*)(&a_lds[((wi << 6) + (f << 4) + l15)*72 + ko]);
        bfr[f] = *(const bf16x8*)(&b_lds[((wj << 6) + (f << 4) + l15)*72 + ko]);
      }
      #pragma unroll
      for (int i = 0; i < 4; ++i)
        #pragma unroll
        for (int j = 0; j < 4; ++j)
          acc[i][j] = __builtin_amdgcn_mfma_f32_16x16x32_bf16(af[i], bfr[j], acc[i][j], 0, 0, 0);
    }
  }
  const size_t ob = (size_t)c*NN;
  #pragma unroll
  for (int i = 0; i < 4; ++i)
    #pragma unroll
    for (int j = 0; j < 4; ++j) {
      const int gj = (jt << 7) + (wj << 6) + (j << 4) + l15;
      #pragma unroll
      for (int r = 0; r < 4; ++r) {
        const int gi = (it << 7) + (wi << 6) + (i << 4) + (l4 << 2) + r;
        Vt[ob + (size_t)gi*512 + gj] = f2bf(acc[i][j][r]);
      }
    }
}

// ---------------- K3: LN(vals) @ W'^T + gate + mask ----------------
// block = (i, j0..j0+127). D[o][jj] = sum_c W'[o][c] * v[c][jj]
__global__ __launch_bounds__(256)
void k3_out(const u16t* __restrict__ Vt, const u16t* __restrict__ Gm,
            const u16t* __restrict__ w3, const float* __restrict__ S1,
            const float* __restrict__ S2, const float* __restrict__ msk,
            float* __restrict__ out) {
  __shared__ u16t v_lds[128*130];   // [c][jj], stride 130 (conflict-free u16 gathers)
  __shared__ u16t w_lds[128*136];
  __shared__ float ps[2][128], pq[2][128];
  __shared__ float mu_s[128], rs_s[128];
  const int t = threadIdx.x;
  const int blk = blockIdx.x;
  const int i  = blk >> 2;
  const int j0 = (blk & 3) << 7;

  stage_w(w_lds, w3, t);
  {
    const size_t base = (size_t)i*512 + j0;
    #pragma unroll 8
    for (int itr = 0; itr < 32; ++itr) {
      const int ci = (itr << 8) + t;
      const int c = ci >> 6, jc = ci & 63;
      const u32t vv = *(const u32t*)(Vt + (size_t)c*NN + base + (jc << 1));
      *(u32t*)((char*)v_lds + c*260 + (jc << 2)) = vv;
    }
  }
  __syncthreads();
  {
    const int jj = t & 127, h = t >> 7;
    float s = 0.f, q = 0.f;
    #pragma unroll 8
    for (int cc = 0; cc < 64; ++cc) {
      const float xv = bf2f(v_lds[(h*64 + cc)*130 + jj]);
      s += xv; q += xv*xv;
    }
    ps[h][jj] = s; pq[h][jj] = q;
  }
  __syncthreads();
  if (t < 128) {
    const float s = ps[0][t] + ps[1][t], q = pq[0][t] + pq[1][t];
    const float mu = s * 0.0078125f;
    const float var = q * 0.0078125f - mu*mu;
    mu_s[t] = mu;
    rs_s[t] = rsqrtf(var + EPSV);
  }
  __syncthreads();

  const int wv = t >> 6, l = t & 63;
  const int l15 = l & 15, l4 = l >> 4;
  const f32x4 Z4 = {0.f, 0.f, 0.f, 0.f};
  f32x4 acc[2][8];
  #pragma unroll
  for (int of = 0; of < 2; ++of)
    #pragma unroll
    for (int jf = 0; jf < 8; ++jf) acc[of][jf] = Z4;

  #pragma unroll
  for (int ks = 0; ks < 4; ++ks) {
    const int ko = (ks << 5) + (l4 << 3);
    bf16x8 a0 = *(const bf16x8*)(&w_lds[((wv << 5) + l15)*136 + ko]);
    bf16x8 a1 = *(const bf16x8*)(&w_lds[((wv << 5) + 16 + l15)*136 + ko]);
    #pragma unroll
    for (int jf = 0; jf < 8; ++jf) {
      const int jj = (jf << 4) + l15;
      bf16x8 b;
      #pragma unroll
      for (int e = 0; e < 8; ++e) b[e] = (short)v_lds[(ko + e)*130 + jj];
      acc[0][jf] = __builtin_amdgcn_mfma_f32_16x16x32_bf16(a0, b, acc[0][jf], 0, 0, 0);
      acc[1][jf] = __builtin_amdgcn_mfma_f32_16x16x32_bf16(a1, b, acc[1][jf], 0, 0, 0);
    }
  }

  #pragma unroll
  for (int of = 0; of < 2; ++of) {
    const int obs = (wv << 5) + (of << 4) + (l4 << 2);
    const f32x4 s1v = *(const f32x4*)(S1 + obs);
    const f32x4 s2v = *(const f32x4*)(S2 + obs);
    #pragma unroll
    for (int jf = 0; jf < 8; ++jf) {
      const int jj = (jf << 4) + l15;
      const float mu = mu_s[jj], rs = rs_s[jj];
      const size_t row = (size_t)i*512 + j0 + jj;
      const float mk = msk[row];
      const ushort4 gv = *(const ushort4*)(Gm + row*128 + obs);
      f32x4 o;
      o[0] = bf2f(gv.x) * (rs*(acc[of][jf][0] - mu*s1v[0]) + s2v[0]) * mk;
      o[1] = bf2f(gv.y) * (rs*(acc[of][jf][1] - mu*s1v[1]) + s2v[1]) * mk;
      o[2] = bf2f(gv.z) * (rs*(acc[of][jf][2] - mu*s1v[2]) + s2v[2]) * mk;
      o[3] = bf2f(gv.w) * (rs*(acc[of][jf][3] - mu*s1v[3]) + s2v[3]) * mk;
      *(f32x4*)(out + row*128 + obs) = o;
    }
  }
}

extern "C" void kernel_launch(void* const* d_in, const int* in_sizes, int n_in,
                              void* d_out, int out_size, void* d_ws, size_t ws_size,
                              hipStream_t stream) {
  const float* pair  = (const float*)d_in[0];
  const float* msk   = (const float*)d_in[1];
  const float* lnpw  = (const float*)d_in[2];
  const float* lnpb  = (const float*)d_in[3];
  const float* lnow  = (const float*)d_in[4];
  const float* lnob  = (const float*)d_in[5];
  const float* g1w   = (const float*)d_in[6];
  const float* g1b   = (const float*)d_in[7];
  const float* g2w   = (const float*)d_in[8];
  const float* g2b   = (const float*)d_in[9];
  const float* l1w   = (const float*)d_in[10];
  const float* l1b   = (const float*)d_in[11];
  const float* l2w   = (const float*)d_in[12];
  const float* l2b   = (const float*)d_in[13];
  const float* gatew = (const float*)d_in[14];
  const float* gateb = (const float*)d_in[15];
  const float* outw  = (const float*)d_in[16];
  const float* outb  = (const float*)d_in[17];
  float* out = (float*)d_out;

  char* ws = (char*)d_ws;
  u16t* At = (u16t*)(ws);                          // 64 MB
  u16t* Bt = (u16t*)(ws + 67108864);               // 64 MB
  u16t* Gm = (u16t*)(ws + 134217728);              // 64 MB
  u16t* Vt = (u16t*)(ws + 201326592);              // 64 MB
  u16t* W5 = (u16t*)(ws + 268435456);              // 160 KB
  u16t* W3 = (u16t*)(ws + 268599296);              // 32 KB
  float* S1 = (float*)(ws + 268632064);
  float* S2 = (float*)(ws + 268632576);

  k0_prep<<<128, 64, 0, stream>>>(g1w, l1w, g2w, l2w, gatew, outw, outb, lnow, lnob, W5, W3, S1, S2);
  k1_fused<<<2048, 256, 0, stream>>>(pair, msk, lnpw, lnpb, W5, g1b, l1b, g2b, l2b, gateb, At, Bt, Gm);
  k2_tri<<<2048, 256, 0, stream>>>(At, Bt, Vt);
  k3_out<<<2048, 256, 0, stream>>>(Vt, Gm, W3, S1, S2, msk, out);
}

// Round 5
// 409.604 us; speedup vs baseline: 1.0259x; 1.0259x over previous
//
#include <hip/hip_runtime.h>
#include <stdint.h>

#define NN 262144            // 512*512
#define EPSV 1e-5f

typedef float f32x4 __attribute__((ext_vector_type(4)));
typedef short bf16x8 __attribute__((ext_vector_type(8)));
typedef unsigned short u16t;
typedef unsigned int u32t;

__device__ __forceinline__ u16t f2bf(float f) {
  u32t u = __builtin_bit_cast(u32t, f);
  u += 0x7fff + ((u >> 16) & 1);           // RNE
  return (u16t)(u >> 16);
}
__device__ __forceinline__ float bf2f(u16t h) {
  u32t u = ((u32t)h) << 16;
  return __builtin_bit_cast(float, u);
}
__device__ __forceinline__ float sigm(float x) { return 1.0f / (1.0f + __expf(-x)); }

// ---------------- K0: weight prep ----------------
// w5: [5][128][128] bf16 = {g1,l1,g2,l2,gate}; w3: W'[o][c]=out_w*ln_out_w bf16
// S1[o] = sum_c W'[o][c]; S2[o] = sum_c ln_out_b[c]*out_w[o][c] + out_b[o]
__global__ void k0_prep(const float* __restrict__ g1w, const float* __restrict__ l1w,
                        const float* __restrict__ g2w, const float* __restrict__ l2w,
                        const float* __restrict__ gatew,
                        const float* __restrict__ outw, const float* __restrict__ outb,
                        const float* __restrict__ lnow, const float* __restrict__ lnob,
                        u16t* __restrict__ w5, u16t* __restrict__ w3,
                        float* __restrict__ S1, float* __restrict__ S2) {
  const int o = blockIdx.x;
  const int t = threadIdx.x;     // 64 threads
  float s1 = 0.f, s2 = 0.f;
  #pragma unroll
  for (int h = 0; h < 2; ++h) {
    const int c = t + 64*h;
    const int idx = o*128 + c;
    w5[0*16384 + idx] = f2bf(g1w[idx]);
    w5[1*16384 + idx] = f2bf(l1w[idx]);
    w5[2*16384 + idx] = f2bf(g2w[idx]);
    w5[3*16384 + idx] = f2bf(l2w[idx]);
    w5[4*16384 + idx] = f2bf(gatew[idx]);
    const float ow = outw[idx];
    const float wp = ow * lnow[c];
    w3[idx] = f2bf(wp);
    s1 += wp;
    s2 += lnob[c] * ow;
  }
  #pragma unroll
  for (int m = 1; m < 64; m <<= 1) { s1 += __shfl_xor(s1, m); s2 += __shfl_xor(s2, m); }
  if (t == 0) { S1[o] = s1; S2[o] = s2 + outb[o]; }
}

// stage a [128][128] bf16 matrix into padded LDS [128][136]
__device__ __forceinline__ void stage_w(u16t* dst_lds, const u16t* __restrict__ src, int t) {
  #pragma unroll
  for (int it = 0; it < 8; ++it) {
    const int ci = (it << 8) + t;
    const int row = ci >> 4, ch = ci & 15;
    *(bf16x8*)(dst_lds + row*136 + (ch << 3)) = *(const bf16x8*)(src + (row << 7) + (ch << 3));
  }
}

// C[128 rows][128 cols] = z @ W^T over K=128 (both LDS [128][136], row-major, read as row l&15 + 8 contig k)
__device__ __forceinline__ void gemm128(const u16t* zl, const u16t* wl,
                                        int rowbase, int l15, int l4, f32x4 acc[2][8]) {
  const f32x4 Z4 = {0.f, 0.f, 0.f, 0.f};
  #pragma unroll
  for (int rf = 0; rf < 2; ++rf)
    #pragma unroll
    for (int cf = 0; cf < 8; ++cf) acc[rf][cf] = Z4;
  #pragma unroll
  for (int ks = 0; ks < 4; ++ks) {
    const int ko = (ks << 5) + (l4 << 3);
    bf16x8 a0 = *(const bf16x8*)(zl + (rowbase + l15)*136 + ko);
    bf16x8 a1 = *(const bf16x8*)(zl + (rowbase + 16 + l15)*136 + ko);
    #pragma unroll
    for (int cf = 0; cf < 8; ++cf) {
      bf16x8 b = *(const bf16x8*)(wl + ((cf << 4) + l15)*136 + ko);
      acc[0][cf] = __builtin_amdgcn_mfma_f32_16x16x32_bf16(a0, b, acc[0][cf], 0, 0, 0);
      acc[1][cf] = __builtin_amdgcn_mfma_f32_16x16x32_bf16(a1, b, acc[1][cf], 0, 0, 0);
    }
  }
}

// ---------------- K1: LN + 5 linears ----------------
// block = 128 rows of (i,k)-space. Outputs: At/Bt [c][i][k] bf16, G [i][j][c] bf16
// KNOWN-GOOD (R1, absmax 0.031). Three rewrites (64-row geometry variants)
// all failed 0.10-0.18 with arithmetic-identical math — do NOT restructure
// this kernel without an on-device bisect.
__global__ __launch_bounds__(256)
void k1_fused(const float* __restrict__ pair, const float* __restrict__ msk,
              const float* __restrict__ lnpw, const float* __restrict__ lnpb,
              const u16t* __restrict__ w5,
              const float* __restrict__ g1b, const float* __restrict__ l1b,
              const float* __restrict__ g2b, const float* __restrict__ l2b,
              const float* __restrict__ gateb,
              u16t* __restrict__ At, u16t* __restrict__ Bt, u16t* __restrict__ Gm) {
  __shared__ u16t z_lds[128*136];
  __shared__ u16t w_lds[128*136];   // weight tile; reused as transpose-staging
  const int t = threadIdx.x;
  const int blk = blockIdx.x;
  const int r0 = blk << 7;          // global row base (i*512+k space)
  const int x  = blk >> 2;          // i
  const int y0 = (blk & 3) << 7;    // k base

  // Phase A: layernorm -> z_lds bf16
  {
    const int c = (t & 31) << 2;
    const f32x4 lw = *(const f32x4*)(lnpw + c);
    const f32x4 lb = *(const f32x4*)(lnpb + c);
    #pragma unroll
    for (int v = 0; v < 16; ++v) {
      const int row = (v << 3) + (t >> 5);
      f32x4 xv = *(const f32x4*)(pair + (size_t)(r0 + row)*128 + c);
      float s = xv[0] + xv[1] + xv[2] + xv[3];
      float q = xv[0]*xv[0] + xv[1]*xv[1] + xv[2]*xv[2] + xv[3]*xv[3];
      #pragma unroll
      for (int m = 1; m <= 16; m <<= 1) { s += __shfl_xor(s, m); q += __shfl_xor(q, m); }
      const float mu = s * 0.0078125f;
      const float var = q * 0.0078125f - mu*mu;
      const float rs = rsqrtf(var + EPSV);
      const u32t lo = (u32t)f2bf((xv[0]-mu)*rs*lw[0]+lb[0]) | ((u32t)f2bf((xv[1]-mu)*rs*lw[1]+lb[1]) << 16);
      const u32t hi = (u32t)f2bf((xv[2]-mu)*rs*lw[2]+lb[2]) | ((u32t)f2bf((xv[3]-mu)*rs*lw[3]+lb[3]) << 16);
      *(uint2*)(&z_lds[row*136 + c]) = make_uint2(lo, hi);
    }
  }
  __syncthreads();

  const int wv = t >> 6, l = t & 63;
  const int l15 = l & 15, l4 = l >> 4;
  const int rowbase = wv << 5;
  f32x4 accg[2][8], accl[2][8];

  // two (gate,linear) pairs -> A then B
  #pragma unroll 1
  for (int p = 0; p < 2; ++p) {
    const float* gbp = p ? g2b : g1b;
    const float* lbp = p ? l2b : l1b;
    u16t* dst = p ? Bt : At;
    stage_w(w_lds, w5 + (size_t)(2*p)*16384, t); __syncthreads();
    gemm128(z_lds, w_lds, rowbase, l15, l4, accg);
    __syncthreads();
    stage_w(w_lds, w5 + (size_t)(2*p+1)*16384, t); __syncthreads();
    gemm128(z_lds, w_lds, rowbase, l15, l4, accl);
    __syncthreads();   // all waves done reading w_lds; reuse as transpose staging [c][r]
    #pragma unroll
    for (int rf = 0; rf < 2; ++rf) {
      const int rb = rowbase + (rf << 4) + (l4 << 2);
      const f32x4 m4 = *(const f32x4*)(msk + r0 + rb);
      #pragma unroll
      for (int cf = 0; cf < 8; ++cf) {
        const int c = (cf << 4) + l15;
        const float bg = gbp[c], bl = lbp[c];
        const float v0 = sigm(accg[rf][cf][0] + bg) * (accl[rf][cf][0] + bl) * m4[0];
        const float v1 = sigm(accg[rf][cf][1] + bg) * (accl[rf][cf][1] + bl) * m4[1];
        const float v2 = sigm(accg[rf][cf][2] + bg) * (accl[rf][cf][2] + bl) * m4[2];
        const float v3 = sigm(accg[rf][cf][3] + bg) * (accl[rf][cf][3] + bl) * m4[3];
        const u32t lo = (u32t)f2bf(v0) | ((u32t)f2bf(v1) << 16);
        const u32t hi = (u32t)f2bf(v2) | ((u32t)f2bf(v3) << 16);
        *(uint2*)(&w_lds[c*136 + rb]) = make_uint2(lo, hi);
      }
    }
    __syncthreads();
    // coalesced channel-major write: [c][x*512 + y0 + r]
    #pragma unroll
    for (int qq = 0; qq < 32; ++qq) {
      const int c = (wv << 5) + qq;
      const u32t d = *(const u32t*)(&w_lds[c*136 + (l << 1)]);
      *(u32t*)(dst + (size_t)c*NN + (size_t)x*512 + y0 + (l << 1)) = d;
    }
    __syncthreads();
  }

  // gate: G = sigmoid(z@gate^T + b), layout [row][c]
  stage_w(w_lds, w5 + (size_t)4*16384, t); __syncthreads();
  gemm128(z_lds, w_lds, rowbase, l15, l4, accg);
  #pragma unroll
  for (int rf = 0; rf < 2; ++rf) {
    #pragma unroll
    for (int cf = 0; cf < 8; ++cf) {
      const int c = (cf << 4) + l15;
      const float bg = gateb[c];
      #pragma unroll
      for (int r = 0; r < 4; ++r) {
        const int row = rowbase + (rf << 4) + (l4 << 2) + r;
        Gm[(size_t)(r0 + row)*128 + c] = f2bf(sigm(accg[rf][cf][r] + bg));
      }
    }
  }
}

// ---------------- K2: per-channel triangle GEMM ----------------
// vals[c][i][j] = sum_k A[c][i][k] * B[c][j][k]; 128x128 tile, K=512
__global__ __launch_bounds__(256)
void k2_tri(const u16t* __restrict__ At, const u16t* __restrict__ Bt, u16t* __restrict__ Vt) {
  __shared__ u16t a_lds[128*72];
  __shared__ u16t b_lds[128*72];
  const int t = threadIdx.x;
  // XCD swizzle (bit-identical: pure block-id permutation, bijective for 2048=8*256):
  // consecutive dispatch ids round-robin over XCDs -> give each XCD a contiguous
  // run of logical tiles so a channel's A/B panels stay L2-resident.
  const int obid = blockIdx.x;
  const int blk = ((obid & 7) << 8) + (obid >> 3);
  const int c  = blk >> 4;
  const int it = (blk >> 2) & 3;
  const int jt = blk & 3;
  const u16t* Ab = At + (size_t)c*NN + (size_t)(it << 7)*512;
  const u16t* Bb = Bt + (size_t)c*NN + (size_t)(jt << 7)*512;
  const int wv = t >> 6, l = t & 63;
  const int l15 = l & 15, l4 = l >> 4;
  const int wi = wv >> 1, wj = wv & 1;
  const int srow = t >> 3, sch = t & 7;

  const f32x4 Z4 = {0.f, 0.f, 0.f, 0.f};
  f32x4 acc[4][4];
  #pragma unroll
  for (int i = 0; i < 4; ++i)
    #pragma unroll
    for (int j = 0; j < 4; ++j) acc[i][j] = Z4;

  for (int kt = 0; kt < 8; ++kt) {
    const int kb = kt << 6;
    bf16x8 ra[4], rb[4];
    #pragma unroll
    for (int is = 0; is < 4; ++is) {
      const int row = (is << 5) + srow;
      ra[is] = *(const bf16x8*)(Ab + (size_t)row*512 + kb + (sch << 3));
      rb[is] = *(const bf16x8*)(Bb + (size_t)row*512 + kb + (sch << 3));
    }
    __syncthreads();                // previous iter's LDS reads done
    #pragma unroll
    for (int is = 0; is < 4; ++is) {
      const int row = (is << 5) + srow;
      *(bf16x8*)(&a_lds[row*72 + (sch << 3)]) = ra[is];
      *(bf16x8*)(&b_lds[row*72 + (sch << 3)]) = rb[is];
    }
    __syncthreads();
    #pragma unroll
    for (int ks = 0; ks < 2; ++ks) {
      const int ko = (ks << 5) + (l4 << 3);
      bf16x8 af[4], bfr[4];
      #pragma unroll
      for (int f = 0; f < 4; ++f) {
        af[f]  = *(const bf16x8*)(&a_lds[((wi << 6) + (f << 4) + l15)*72 + ko]);
        bfr[f] = *(const bf16x8*)(&b_lds[((wj << 6) + (f << 4) + l15)*72 + ko]);
      }
      #pragma unroll
      for (int i = 0; i < 4; ++i)
        #pragma unroll
        for (int j = 0; j < 4; ++j)
          acc[i][j] = __builtin_amdgcn_mfma_f32_16x16x32_bf16(af[i], bfr[j], acc[i][j], 0, 0, 0);
    }
  }
  const size_t ob = (size_t)c*NN;
  #pragma unroll
  for (int i = 0; i < 4; ++i)
    #pragma unroll
    for (int j = 0; j < 4; ++j) {
      const int gj = (jt << 7) + (wj << 6) + (j << 4) + l15;
      #pragma unroll
      for (int r = 0; r < 4; ++r) {
        const int gi = (it << 7) + (wi << 6) + (i << 4) + (l4 << 2) + r;
        Vt[ob + (size_t)gi*512 + gj] = f2bf(acc[i][j][r]);
      }
    }
}

// ---------------- K3: LN(vals) @ W'^T + gate + mask ----------------
// block = (i, j0..j0+127). D[o][jj] = sum_c W'[o][c] * v[c][jj]
__global__ __launch_bounds__(256)
void k3_out(const u16t* __restrict__ Vt, const u16t* __restrict__ Gm,
            const u16t* __restrict__ w3, const float* __restrict__ S1,
            const float* __restrict__ S2, const float* __restrict__ msk,
            float* __restrict__ out) {
  __shared__ u16t v_lds[128*130];   // [c][jj], stride 130 (conflict-free u16 gathers)
  __shared__ u16t w_lds[128*136];
  __shared__ float ps[2][128], pq[2][128];
  __shared__ float mu_s[128], rs_s[128];
  const int t = threadIdx.x;
  const int blk = blockIdx.x;
  const int i  = blk >> 2;
  const int j0 = (blk & 3) << 7;

  stage_w(w_lds, w3, t);
  {
    const size_t base = (size_t)i*512 + j0;
    #pragma unroll 8
    for (int itr = 0; itr < 32; ++itr) {
      const int ci = (itr << 8) + t;
      const int c = ci >> 6, jc = ci & 63;
      const u32t vv = *(const u32t*)(Vt + (size_t)c*NN + base + (jc << 1));
      *(u32t*)((char*)v_lds + c*260 + (jc << 2)) = vv;
    }
  }
  __syncthreads();
  {
    const int jj = t & 127, h = t >> 7;
    float s = 0.f, q = 0.f;
    #pragma unroll 8
    for (int cc = 0; cc < 64; ++cc) {
      const float xv = bf2f(v_lds[(h*64 + cc)*130 + jj]);
      s += xv; q += xv*xv;
    }
    ps[h][jj] = s; pq[h][jj] = q;
  }
  __syncthreads();
  if (t < 128) {
    const float s = ps[0][t] + ps[1][t], q = pq[0][t] + pq[1][t];
    const float mu = s * 0.0078125f;
    const float var = q * 0.0078125f - mu*mu;
    mu_s[t] = mu;
    rs_s[t] = rsqrtf(var + EPSV);
  }
  __syncthreads();

  const int wv = t >> 6, l = t & 63;
  const int l15 = l & 15, l4 = l >> 4;
  const f32x4 Z4 = {0.f, 0.f, 0.f, 0.f};
  f32x4 acc[2][8];
  #pragma unroll
  for (int of = 0; of < 2; ++of)
    #pragma unroll
    for (int jf = 0; jf < 8; ++jf) acc[of][jf] = Z4;

  #pragma unroll
  for (int ks = 0; ks < 4; ++ks) {
    const int ko = (ks << 5) + (l4 << 3);
    bf16x8 a0 = *(const bf16x8*)(&w_lds[((wv << 5) + l15)*136 + ko]);
    bf16x8 a1 = *(const bf16x8*)(&w_lds[((wv << 5) + 16 + l15)*136 + ko]);
    #pragma unroll
    for (int jf = 0; jf < 8; ++jf) {
      const int jj = (jf << 4) + l15;
      bf16x8 b;
      #pragma unroll
      for (int e = 0; e < 8; ++e) b[e] = (short)v_lds[(ko + e)*130 + jj];
      acc[0][jf] = __builtin_amdgcn_mfma_f32_16x16x32_bf16(a0, b, acc[0][jf], 0, 0, 0);
      acc[1][jf] = __builtin_amdgcn_mfma_f32_16x16x32_bf16(a1, b, acc[1][jf], 0, 0, 0);
    }
  }

  #pragma unroll
  for (int of = 0; of < 2; ++of) {
    const int obs = (wv << 5) + (of << 4) + (l4 << 2);
    const f32x4 s1v = *(const f32x4*)(S1 + obs);
    const f32x4 s2v = *(const f32x4*)(S2 + obs);
    #pragma unroll
    for (int jf = 0; jf < 8; ++jf) {
      const int jj = (jf << 4) + l15;
      const float mu = mu_s[jj], rs = rs_s[jj];
      const size_t row = (size_t)i*512 + j0 + jj;
      const float mk = msk[row];
      const ushort4 gv = *(const ushort4*)(Gm + row*128 + obs);
      f32x4 o;
      o[0] = bf2f(gv.x) * (rs*(acc[of][jf][0] - mu*s1v[0]) + s2v[0]) * mk;
      o[1] = bf2f(gv.y) * (rs*(acc[of][jf][1] - mu*s1v[1]) + s2v[1]) * mk;
      o[2] = bf2f(gv.z) * (rs*(acc[of][jf][2] - mu*s1v[2]) + s2v[2]) * mk;
      o[3] = bf2f(gv.w) * (rs*(acc[of][jf][3] - mu*s1v[3]) + s2v[3]) * mk;
      *(f32x4*)(out + row*128 + obs) = o;
    }
  }
}

extern "C" void kernel_launch(void* const* d_in, const int* in_sizes, int n_in,
                              void* d_out, int out_size, void* d_ws, size_t ws_size,
                              hipStream_t stream) {
  const float* pair  = (const float*)d_in[0];
  const float* msk   = (const float*)d_in[1];
  const float* lnpw  = (const float*)d_in[2];
  const float* lnpb  = (const float*)d_in[3];
  const float* lnow  = (const float*)d_in[4];
  const float* lnob  = (const float*)d_in[5];
  const float* g1w   = (const float*)d_in[6];
  const float* g1b   = (const float*)d_in[7];
  const float* g2w   = (const float*)d_in[8];
  const float* g2b   = (const float*)d_in[9];
  const float* l1w   = (const float*)d_in[10];
  const float* l1b   = (const float*)d_in[11];
  const float* l2w   = (const float*)d_in[12];
  const float* l2b   = (const float*)d_in[13];
  const float* gatew = (const float*)d_in[14];
  const float* gateb = (const float*)d_in[15];
  const float* outw  = (const float*)d_in[16];
  const float* outb  = (const float*)d_in[17];
  float* out = (float*)d_out;

  char* ws = (char*)d_ws;
  u16t* At = (u16t*)(ws);                          // 64 MB
  u16t* Bt = (u16t*)(ws + 67108864);               // 64 MB
  u16t* Gm = (u16t*)(ws + 134217728);              // 64 MB
  u16t* Vt = (u16t*)(ws + 201326592);               // 64 MB
  u16t* W5 = (u16t*)(ws + 268435456);              // 160 KB
  u16t* W3 = (u16t*)(ws + 268599296);              // 32 KB
  float* S1 = (float*)(ws + 268632064);
  float* S2 = (float*)(ws + 268632576);

  k0_prep<<<128, 64, 0, stream>>>(g1w, l1w, g2w, l2w, gatew, outw, outb, lnow, lnob, W5, W3, S1, S2);
  k1_fused<<<2048, 256, 0, stream>>>(pair, msk, lnpw, lnpb, W5, g1b, l1b, g2b, l2b, gateb, At, Bt, Gm);
  k2_tri<<<2048, 256, 0, stream>>>(At, Bt, Vt);
  k3_out<<<2048, 256, 0, stream>>>(Vt, Gm, W3, S1, S2, msk, out);
}

// Round 7
// 401.669 us; speedup vs baseline: 1.0461x; 1.0198x over previous
//
#include <hip/hip_runtime.h>
#include <stdint.h>

#define NN 262144            // 512*512
#define EPSV 1e-5f

typedef float f32x4 __attribute__((ext_vector_type(4)));
typedef short bf16x8 __attribute__((ext_vector_type(8)));
typedef unsigned short u16t;
typedef unsigned int u32t;

__device__ __forceinline__ u16t f2bf(float f) {
  u32t u = __builtin_bit_cast(u32t, f);
  u += 0x7fff + ((u >> 16) & 1);           // RNE
  return (u16t)(u >> 16);
}
__device__ __forceinline__ float bf2f(u16t h) {
  u32t u = ((u32t)h) << 16;
  return __builtin_bit_cast(float, u);
}
__device__ __forceinline__ float sigm(float x) { return 1.0f / (1.0f + __expf(-x)); }

// ---------------- K0: weight prep ----------------
// w5: [5][128][128] bf16 = {g1,l1,g2,l2,gate}; w3: W'[o][c]=out_w*ln_out_w bf16
// S1[o] = sum_c W'[o][c]; S2[o] = sum_c ln_out_b[c]*out_w[o][c] + out_b[o]
__global__ void k0_prep(const float* __restrict__ g1w, const float* __restrict__ l1w,
                        const float* __restrict__ g2w, const float* __restrict__ l2w,
                        const float* __restrict__ gatew,
                        const float* __restrict__ outw, const float* __restrict__ outb,
                        const float* __restrict__ lnow, const float* __restrict__ lnob,
                        u16t* __restrict__ w5, u16t* __restrict__ w3,
                        float* __restrict__ S1, float* __restrict__ S2) {
  const int o = blockIdx.x;
  const int t = threadIdx.x;     // 64 threads
  float s1 = 0.f, s2 = 0.f;
  #pragma unroll
  for (int h = 0; h < 2; ++h) {
    const int c = t + 64*h;
    const int idx = o*128 + c;
    w5[0*16384 + idx] = f2bf(g1w[idx]);
    w5[1*16384 + idx] = f2bf(l1w[idx]);
    w5[2*16384 + idx] = f2bf(g2w[idx]);
    w5[3*16384 + idx] = f2bf(l2w[idx]);
    w5[4*16384 + idx] = f2bf(gatew[idx]);
    const float ow = outw[idx];
    const float wp = ow * lnow[c];
    w3[idx] = f2bf(wp);
    s1 += wp;
    s2 += lnob[c] * ow;
  }
  #pragma unroll
  for (int m = 1; m < 64; m <<= 1) { s1 += __shfl_xor(s1, m); s2 += __shfl_xor(s2, m); }
  if (t == 0) { S1[o] = s1; S2[o] = s2 + outb[o]; }
}

// stage a [128][128] bf16 matrix into padded LDS [128][136]
__device__ __forceinline__ void stage_w(u16t* dst_lds, const u16t* __restrict__ src, int t) {
  #pragma unroll
  for (int it = 0; it < 8; ++it) {
    const int ci = (it << 8) + t;
    const int row = ci >> 4, ch = ci & 15;
    *(bf16x8*)(dst_lds + row*136 + (ch << 3)) = *(const bf16x8*)(src + (row << 7) + (ch << 3));
  }
}

// C[128 rows][128 cols] = z @ W^T over K=128 (both LDS [128][136], row-major, read as row l&15 + 8 contig k)
__device__ __forceinline__ void gemm128(const u16t* zl, const u16t* wl,
                                        int rowbase, int l15, int l4, f32x4 acc[2][8]) {
  const f32x4 Z4 = {0.f, 0.f, 0.f, 0.f};
  #pragma unroll
  for (int rf = 0; rf < 2; ++rf)
    #pragma unroll
    for (int cf = 0; cf < 8; ++cf) acc[rf][cf] = Z4;
  #pragma unroll
  for (int ks = 0; ks < 4; ++ks) {
    const int ko = (ks << 5) + (l4 << 3);
    bf16x8 a0 = *(const bf16x8*)(zl + (rowbase + l15)*136 + ko);
    bf16x8 a1 = *(const bf16x8*)(zl + (rowbase + 16 + l15)*136 + ko);
    #pragma unroll
    for (int cf = 0; cf < 8; ++cf) {
      bf16x8 b = *(const bf16x8*)(wl + ((cf << 4) + l15)*136 + ko);
      acc[0][cf] = __builtin_amdgcn_mfma_f32_16x16x32_bf16(a0, b, acc[0][cf], 0, 0, 0);
      acc[1][cf] = __builtin_amdgcn_mfma_f32_16x16x32_bf16(a1, b, acc[1][cf], 0, 0, 0);
    }
  }
}

// ---------------- K1: LN + 5 linears ----------------
// KNOWN-GOOD (R1/R5, absmax exactly 0.03125, deterministic). FROZEN.
// 4 restructures (64-row, global-weights, path-split) all failed 0.10-0.18
// with arithmetic-identical math; defect not statically localizable. Do NOT
// edit this kernel or its grid (2048).
__global__ __launch_bounds__(256)
void k1_fused(const float* __restrict__ pair, const float* __restrict__ msk,
              const float* __restrict__ lnpw, const float* __restrict__ lnpb,
              const u16t* __restrict__ w5,
              const float* __restrict__ g1b, const float* __restrict__ l1b,
              const float* __restrict__ g2b, const float* __restrict__ l2b,
              const float* __restrict__ gateb,
              u16t* __restrict__ At, u16t* __restrict__ Bt, u16t* __restrict__ Gm) {
  __shared__ u16t z_lds[128*136];
  __shared__ u16t w_lds[128*136];   // weight tile; reused as transpose-staging
  const int t = threadIdx.x;
  const int blk = blockIdx.x;
  const int r0 = blk << 7;          // global row base (i*512+k space)
  const int x  = blk >> 2;          // i
  const int y0 = (blk & 3) << 7;    // k base

  // Phase A: layernorm -> z_lds bf16
  {
    const int c = (t & 31) << 2;
    const f32x4 lw = *(const f32x4*)(lnpw + c);
    const f32x4 lb = *(const f32x4*)(lnpb + c);
    #pragma unroll
    for (int v = 0; v < 16; ++v) {
      const int row = (v << 3) + (t >> 5);
      f32x4 xv = *(const f32x4*)(pair + (size_t)(r0 + row)*128 + c);
      float s = xv[0] + xv[1] + xv[2] + xv[3];
      float q = xv[0]*xv[0] + xv[1]*xv[1] + xv[2]*xv[2] + xv[3]*xv[3];
      #pragma unroll
      for (int m = 1; m <= 16; m <<= 1) { s += __shfl_xor(s, m); q += __shfl_xor(q, m); }
      const float mu = s * 0.0078125f;
      const float var = q * 0.0078125f - mu*mu;
      const float rs = rsqrtf(var + EPSV);
      const u32t lo = (u32t)f2bf((xv[0]-mu)*rs*lw[0]+lb[0]) | ((u32t)f2bf((xv[1]-mu)*rs*lw[1]+lb[1]) << 16);
      const u32t hi = (u32t)f2bf((xv[2]-mu)*rs*lw[2]+lb[2]) | ((u32t)f2bf((xv[3]-mu)*rs*lw[3]+lb[3]) << 16);
      *(uint2*)(&z_lds[row*136 + c]) = make_uint2(lo, hi);
    }
  }
  __syncthreads();

  const int wv = t >> 6, l = t & 63;
  const int l15 = l & 15, l4 = l >> 4;
  const int rowbase = wv << 5;
  f32x4 accg[2][8], accl[2][8];

  // two (gate,linear) pairs -> A then B
  #pragma unroll 1
  for (int p = 0; p < 2; ++p) {
    const float* gbp = p ? g2b : g1b;
    const float* lbp = p ? l2b : l1b;
    u16t* dst = p ? Bt : At;
    stage_w(w_lds, w5 + (size_t)(2*p)*16384, t); __syncthreads();
    gemm128(z_lds, w_lds, rowbase, l15, l4, accg);
    __syncthreads();
    stage_w(w_lds, w5 + (size_t)(2*p+1)*16384, t); __syncthreads();
    gemm128(z_lds, w_lds, rowbase, l15, l4, accl);
    __syncthreads();   // all waves done reading w_lds; reuse as transpose staging [c][r]
    #pragma unroll
    for (int rf = 0; rf < 2; ++rf) {
      const int rb = rowbase + (rf << 4) + (l4 << 2);
      const f32x4 m4 = *(const f32x4*)(msk + r0 + rb);
      #pragma unroll
      for (int cf = 0; cf < 8; ++cf) {
        const int c = (cf << 4) + l15;
        const float bg = gbp[c], bl = lbp[c];
        const float v0 = sigm(accg[rf][cf][0] + bg) * (accl[rf][cf][0] + bl) * m4[0];
        const float v1 = sigm(accg[rf][cf][1] + bg) * (accl[rf][cf][1] + bl) * m4[1];
        const float v2 = sigm(accg[rf][cf][2] + bg) * (accl[rf][cf][2] + bl) * m4[2];
        const float v3 = sigm(accg[rf][cf][3] + bg) * (accl[rf][cf][3] + bl) * m4[3];
        const u32t lo = (u32t)f2bf(v0) | ((u32t)f2bf(v1) << 16);
        const u32t hi = (u32t)f2bf(v2) | ((u32t)f2bf(v3) << 16);
        *(uint2*)(&w_lds[c*136 + rb]) = make_uint2(lo, hi);
      }
    }
    __syncthreads();
    // coalesced channel-major write: [c][x*512 + y0 + r]
    #pragma unroll
    for (int qq = 0; qq < 32; ++qq) {
      const int c = (wv << 5) + qq;
      const u32t d = *(const u32t*)(&w_lds[c*136 + (l << 1)]);
      *(u32t*)(dst + (size_t)c*NN + (size_t)x*512 + y0 + (l << 1)) = d;
    }
    __syncthreads();
  }

  // gate: G = sigmoid(z@gate^T + b), layout [row][c]
  stage_w(w_lds, w5 + (size_t)4*16384, t); __syncthreads();
  gemm128(z_lds, w_lds, rowbase, l15, l4, accg);
  #pragma unroll
  for (int rf = 0; rf < 2; ++rf) {
    #pragma unroll
    for (int cf = 0; cf < 8; ++cf) {
      const int c = (cf << 4) + l15;
      const float bg = gateb[c];
      #pragma unroll
      for (int r = 0; r < 4; ++r) {
        const int row = rowbase + (rf << 4) + (l4 << 2) + r;
        Gm[(size_t)(r0 + row)*128 + c] = f2bf(sigm(accg[rf][cf][r] + bg));
      }
    }
  }
}

// ---------------- K2 v2: per-channel triangle GEMM, 256x128 tiles ----------------
// vals[c][i][j] = sum_k A[c][i][k] * B[c][j][k]; 1024 blocks x 512 thr (8 waves 4x2,
// wave = 64x64 output = v1's exact acc/register profile). Per-element MFMA chain
// (kt 0..7, ks 0..1) identical to v1 -> Vt bit-identical.
__global__ __launch_bounds__(512)
void k2_tri(const u16t* __restrict__ At, const u16t* __restrict__ Bt, u16t* __restrict__ Vt) {
  __shared__ u16t a_lds[256*72];    // 36,864 B
  __shared__ u16t b_lds[128*72];    // 18,432 B
  const int t = threadIdx.x;
  // XCD swizzle, bijective for 1024 = 8*128: each XCD gets 128 consecutive logical
  // blocks = 16 channels x 8 tiles; a channel's 8 tiles are consecutive -> its
  // 1 MB A/B panels stay L2-resident.
  const int obid = blockIdx.x;
  const int blk = ((obid & 7) << 7) + (obid >> 3);
  const int c   = blk >> 3;          // 0..127
  const int sub = blk & 7;
  const int it  = sub >> 2;          // 0..1  (256-row i-panel)
  const int jt  = sub & 3;           // 0..3  (128-row j-panel)
  const u16t* Ab = At + (size_t)c*NN + (size_t)(it << 8)*512;
  const u16t* Bb = Bt + (size_t)c*NN + (size_t)(jt << 7)*512;
  const int wv = t >> 6, l = t & 63;
  const int l15 = l & 15, l4 = l >> 4;
  const int wi = wv >> 1, wj = wv & 1;   // 4 x 2 waves
  const int srow = t >> 3, sch = t & 7;  // srow 0..63, sch 0..7

  const f32x4 Z4 = {0.f, 0.f, 0.f, 0.f};
  f32x4 acc[4][4];
  #pragma unroll
  for (int i = 0; i < 4; ++i)
    #pragma unroll
    for (int j = 0; j < 4; ++j) acc[i][j] = Z4;

  for (int kt = 0; kt < 8; ++kt) {
    const int kb = kt << 6;
    bf16x8 ra[4], rb[2];
    #pragma unroll
    for (int is = 0; is < 4; ++is) {            // A: 256 rows
      const int row = (is << 6) + srow;
      ra[is] = *(const bf16x8*)(Ab + (size_t)row*512 + kb + (sch << 3));
    }
    #pragma unroll
    for (int is = 0; is < 2; ++is) {            // B: 128 rows
      const int row = (is << 6) + srow;
      rb[is] = *(const bf16x8*)(Bb + (size_t)row*512 + kb + (sch << 3));
    }
    __syncthreads();                // previous iter's LDS reads done
    #pragma unroll
    for (int is = 0; is < 4; ++is) {
      const int row = (is << 6) + srow;
      *(bf16x8*)(&a_lds[row*72 + (sch << 3)]) = ra[is];
    }
    #pragma unroll
    for (int is = 0; is < 2; ++is) {
      const int row = (is << 6) + srow;
      *(bf16x8*)(&b_lds[row*72 + (sch << 3)]) = rb[is];
    }
    __syncthreads();
    #pragma unroll
    for (int ks = 0; ks < 2; ++ks) {
      const int ko = (ks << 5) + (l4 << 3);
      bf16x8 af[4], bfr[4];
      #pragma unroll
      for (int f = 0; f < 4; ++f) {
        af[f]  = *(const bf16x8*)(&a_lds[((wi << 6) + (f << 4) + l15)*72 + ko]);
        bfr[f] = *(const bf16x8*)(&b_lds[((wj << 6) + (f << 4) + l15)*72 + ko]);
      }
      #pragma unroll
      for (int i = 0; i < 4; ++i)
        #pragma unroll
        for (int j = 0; j < 4; ++j)
          acc[i][j] = __builtin_amdgcn_mfma_f32_16x16x32_bf16(af[i], bfr[j], acc[i][j], 0, 0, 0);
    }
  }
  const size_t ob = (size_t)c*NN;
  #pragma unroll
  for (int i = 0; i < 4; ++i)
    #pragma unroll
    for (int j = 0; j < 4; ++j) {
      const int gj = (jt << 7) + (wj << 6) + (j << 4) + l15;
      #pragma unroll
      for (int r = 0; r < 4; ++r) {
        const int gi = (it << 8) + (wi << 6) + (i << 4) + (l4 << 2) + r;
        Vt[ob + (size_t)gi*512 + gj] = f2bf(acc[i][j][r]);
      }
    }
}

// ---------------- K3: LN(vals) @ W'^T + gate + mask ----------------
// block = (i, j0..j0+127). D[o][jj] = sum_c W'[o][c] * v[c][jj]
__global__ __launch_bounds__(256)
void k3_out(const u16t* __restrict__ Vt, const u16t* __restrict__ Gm,
            const u16t* __restrict__ w3, const float* __restrict__ S1,
            const float* __restrict__ S2, const float* __restrict__ msk,
            float* __restrict__ out) {
  __shared__ u16t v_lds[128*130];   // [c][jj], stride 130 (conflict-free u16 gathers)
  __shared__ u16t w_lds[128*136];
  __shared__ float ps[2][128], pq[2][128];
  __shared__ float mu_s[128], rs_s[128];
  const int t = threadIdx.x;
  const int blk = blockIdx.x;
  const int i  = blk >> 2;
  const int j0 = (blk & 3) << 7;

  stage_w(w_lds, w3, t);
  {
    const size_t base = (size_t)i*512 + j0;
    #pragma unroll 8
    for (int itr = 0; itr < 32; ++itr) {
      const int ci = (itr << 8) + t;
      const int c = ci >> 6, jc = ci & 63;
      const u32t vv = *(const u32t*)(Vt + (size_t)c*NN + base + (jc << 1));
      *(u32t*)((char*)v_lds + c*260 + (jc << 2)) = vv;
    }
  }
  __syncthreads();
  {
    const int jj = t & 127, h = t >> 7;
    float s = 0.f, q = 0.f;
    #pragma unroll 8
    for (int cc = 0; cc < 64; ++cc) {
      const float xv = bf2f(v_lds[(h*64 + cc)*130 + jj]);
      s += xv; q += xv*xv;
    }
    ps[h][jj] = s; pq[h][jj] = q;
  }
  __syncthreads();
  if (t < 128) {
    const float s = ps[0][t] + ps[1][t], q = pq[0][t] + pq[1][t];
    const float mu = s * 0.0078125f;
    const float var = q * 0.0078125f - mu*mu;
    mu_s[t] = mu;
    rs_s[t] = rsqrtf(var + EPSV);
  }
  __syncthreads();

  const int wv = t >> 6, l = t & 63;
  const int l15 = l & 15, l4 = l >> 4;
  const f32x4 Z4 = {0.f, 0.f, 0.f, 0.f};
  f32x4 acc[2][8];
  #pragma unroll
  for (int of = 0; of < 2; ++of)
    #pragma unroll
    for (int jf = 0; jf < 8; ++jf) acc[of][jf] = Z4;

  #pragma unroll
  for (int ks = 0; ks < 4; ++ks) {
    const int ko = (ks << 5) + (l4 << 3);
    bf16x8 a0 = *(const bf16x8*)(&w_lds[((wv << 5) + l15)*136 + ko]);
    bf16x8 a1 = *(const bf16x8*)(&w_lds[((wv << 5) + 16 + l15)*136 + ko]);
    #pragma unroll
    for (int jf = 0; jf < 8; ++jf) {
      const int jj = (jf << 4) + l15;
      bf16x8 b;
      #pragma unroll
      for (int e = 0; e < 8; ++e) b[e] = (short)v_lds[(ko + e)*130 + jj];
      acc[0][jf] = __builtin_amdgcn_mfma_f32_16x16x32_bf16(a0, b, acc[0][jf], 0, 0, 0);
      acc[1][jf] = __builtin_amdgcn_mfma_f32_16x16x32_bf16(a1, b, acc[1][jf], 0, 0, 0);
    }
  }

  #pragma unroll
  for (int of = 0; of < 2; ++of) {
    const int obs = (wv << 5) + (of << 4) + (l4 << 2);
    const f32x4 s1v = *(const f32x4*)(S1 + obs);
    const f32x4 s2v = *(const f32x4*)(S2 + obs);
    #pragma unroll
    for (int jf = 0; jf < 8; ++jf) {
      const int jj = (jf << 4) + l15;
      const float mu = mu_s[jj], rs = rs_s[jj];
      const size_t row = (size_t)i*512 + j0 + jj;
      const float mk = msk[row];
      const ushort4 gv = *(const ushort4*)(Gm + row*128 + obs);
      f32x4 o;
      o[0] = bf2f(gv.x) * (rs*(acc[of][jf][0] - mu*s1v[0]) + s2v[0]) * mk;
      o[1] = bf2f(gv.y) * (rs*(acc[of][jf][1] - mu*s1v[1]) + s2v[1]) * mk;
      o[2] = bf2f(gv.z) * (rs*(acc[of][jf][2] - mu*s1v[2]) + s2v[2]) * mk;
      o[3] = bf2f(gv.w) * (rs*(acc[of][jf][3] - mu*s1v[3]) + s2v[3]) * mk;
      *(f32x4*)(out + row*128 + obs) = o;
    }
  }
}

extern "C" void kernel_launch(void* const* d_in, const int* in_sizes, int n_in,
                              void* d_out, int out_size, void* d_ws, size_t ws_size,
                              hipStream_t stream) {
  const float* pair  = (const float*)d_in[0];
  const float* msk   = (const float*)d_in[1];
  const float* lnpw  = (const float*)d_in[2];
  const float* lnpb  = (const float*)d_in[3];
  const float* lnow  = (const float*)d_in[4];
  const float* lnob  = (const float*)d_in[5];
  const float* g1w   = (const float*)d_in[6];
  const float* g1b   = (const float*)d_in[7];
  const float* g2w   = (const float*)d_in[8];
  const float* g2b   = (const float*)d_in[9];
  const float* l1w   = (const float*)d_in[10];
  const float* l1b   = (const float*)d_in[11];
  const float* l2w   = (const float*)d_in[12];
  const float* l2b   = (const float*)d_in[13];
  const float* gatew = (const float*)d_in[14];
  const float* gateb = (const float*)d_in[15];
  const float* outw  = (const float*)d_in[16];
  const float* outb  = (const float*)d_in[17];
  float* out = (float*)d_out;

  char* ws = (char*)d_ws;
  u16t* At = (u16t*)(ws);                          // 64 MB
  u16t* Bt = (u16t*)(ws + 67108864);               // 64 MB
  u16t* Gm = (u16t*)(ws + 134217728);              // 64 MB
  u16t* Vt = (u16t*)(ws + 201326592);              // 64 MB
  u16t* W5 = (u16t*)(ws + 268435456);              // 160 KB
  u16t* W3 = (u16t*)(ws + 268599296);              // 32 KB
  float* S1 = (float*)(ws + 268632064);
  float* S2 = (float*)(ws + 268632576);

  k0_prep<<<128, 64, 0, stream>>>(g1w, l1w, g2w, l2w, gatew, outw, outb, lnow, lnob, W5, W3, S1, S2);
  k1_fused<<<2048, 256, 0, stream>>>(pair, msk, lnpw, lnpb, W5, g1b, l1b, g2b, l2b, gateb, At, Bt, Gm);
  k2_tri<<<1024, 512, 0, stream>>>(At, Bt, Vt);
  k3_out<<<2048, 256, 0, stream>>>(Vt, Gm, W3, S1, S2, msk, out);
}